// Round 1
// 234.058 us; speedup vs baseline: 1.0113x; 1.0113x over previous
//
#include <hip/hip_runtime.h>
#include <math.h>

#define NC 19
#define NB 8
#define HW (512 * 512)
#define CHUNKS 16
#define NG 10      // channel pairs {0,1},...,{16,17}, then {18, counts}
#define TPB 256
#define STRIDE 39  // odd stride in floats: tid*39 covers all 32 banks (gcd(39,32)=1)
#define UNROLL 4   // software-pipeline batch: load 4 iters ahead
#define FT 1024
#define NBLK (NG * CHUNKS * NB)  // 1280 blocks; 1280 % 8 == 0 -> bijective XCD swizzle

typedef float v4f __attribute__((ext_vector_type(4)));
typedef int v4i __attribute__((ext_vector_type(4)));

// Workspace: S_part[NB][CHUNKS][NC][20] floats (194,560 B), unique slot per
// (b,chunk,col) -> no zero-init, no atomics. Row t = class, col c in 0..18 =
// sum of channel c over class-t pixels, col 19 = class-t count.

__global__ __launch_bounds__(TPB) void accum_kernel(const float* __restrict__ seg,
                                                    const int* __restrict__ tgt,
                                                    float* __restrict__ S_part) {
    // Per-thread PRIVATE bins, scalar f32, odd stride (conflict-free, R3/R6-proven).
    // 39*4B*256 = 39.9 KB -> 4 blocks/CU resident, 1280 blocks = 5 per CU exactly.
    __shared__ float bins[TPB * STRIDE];

    const int tid = threadIdx.x;

    // XCD-tile swizzle: HW dispatches block i -> XCD (i % 8). Map each XCD's
    // blocks (bid%8 == x) to a CONTIGUOUS logical range x*160..x*160+159, so the
    // 10 groups of one (chunk,b) tile all land on ONE XCD -> tgt chunk is pulled
    // into that XCD's L2 once and L2-hit by the other 9 blocks (previously each
    // of 8 XCDs re-fetched it from L3: ~67 MB of avoidable die-level traffic).
    const int bid = blockIdx.x;
    const int L = (bid & 7) * (NBLK / 8) + (bid >> 3);  // bijective, 1280 % 8 == 0
    const int g = L % NG;                                // group: fastest within tile
    const int tile = L / NG;                             // 0..127 = (b, chunk)
    const int chunk = tile & (CHUNKS - 1);
    const int b = tile >> 4;                             // CHUNKS == 16

    const bool last = (g == NG - 1);
    const int c0 = 2 * g;

    float* p0 = &bins[tid * STRIDE];
    float* p1 = p0 + NC;
    #pragma unroll
    for (int k = 0; k < STRIDE; ++k) p0[k] = 0.0f;
    // Rows are thread-private until the fold: no barrier needed here.

    const int per_chunk = HW / CHUNKS;  // 16384 pixels
    const size_t pix = (size_t)chunk * per_chunk;
    const v4f* __restrict__ s0 = (const v4f*)(seg + ((size_t)(b * NC + c0)) * HW + pix);
    // Last group: alias s1 to s0 so every issued load is in-bounds even if the
    // compiler if-converts the select below (c0+1 == 19 would read past seg at b==7).
    const v4f* __restrict__ s1 =
        (const v4f*)(seg + ((size_t)(b * NC + (last ? c0 : c0 + 1))) * HW + pix);
    const v4i* __restrict__ tv = (const v4i*)(tgt + (size_t)b * HW + pix);

    const int iters = per_chunk / 4 / TPB;   // 16
    const int nsuper = iters / UNROLL;       // 4
    const v4f ones = {1.0f, 1.0f, 1.0f, 1.0f};

    // Cacheable loads on purpose: harness restores d_in before every replay, so
    // seg+tgt are L3-warm (R5 evidence: 6.2 MB-FETCH replays). nt would forfeit it.
    v4f A0[UNROLL], A1[UNROLL];
    v4i T[UNROLL];
    #pragma unroll
    for (int j = 0; j < UNROLL; ++j) {
        const int v = j * TPB + tid;
        T[j] = tv[v];
        A0[j] = s0[v];
        A1[j] = last ? ones : s1[v];
    }

    for (int s = 0; s < nsuper; ++s) {
        v4f B0[UNROLL] = {}, B1[UNROLL] = {};
        v4i TN[UNROLL] = {};
        if (s + 1 < nsuper) {
            const int base = (s + 1) * UNROLL * TPB + tid;
            #pragma unroll
            for (int j = 0; j < UNROLL; ++j) {
                const int v = base + j * TPB;
                TN[j] = tv[v];
                B0[j] = s0[v];
                B1[j] = last ? ones : s1[v];
            }
        }
        #pragma unroll
        for (int j = 0; j < UNROLL; ++j) {
            const v4i t = T[j];
            // Two independent 4-deep LDS RMW chains (channel c0 / channel c1-or-count).
            p0[t.x] += A0[j].x;  p1[t.x] += A1[j].x;
            p0[t.y] += A0[j].y;  p1[t.y] += A1[j].y;
            p0[t.z] += A0[j].z;  p1[t.z] += A1[j].z;
            p0[t.w] += A0[j].w;  p1[t.w] += A1[j].w;
        }
        #pragma unroll
        for (int j = 0; j < UNROLL; ++j) { T[j] = TN[j]; A0[j] = B0[j]; A1[j] = B1[j]; }
    }
    __syncthreads();

    // Stage 1: fold 256 rows -> 32 rows over the 38 live columns, in-place safe.
    for (int e = tid; e < 32 * 2 * NC; e += TPB) {  // 1216 elements
        const int r = e & 31, c = e >> 5;  // c in 0..37
        float acc = bins[r * STRIDE + c];
        #pragma unroll
        for (int j = 1; j < TPB / 32; ++j) acc += bins[(r + 32 * j) * STRIDE + c];
        bins[r * STRIDE + c] = acc;
    }
    __syncthreads();

    // Stage 2: 38 lanes (wave 0) sum the 32 rows of their column; plain store
    // to this block's unique slots.
    if (tid < 2 * NC) {
        float acc = bins[tid];
        #pragma unroll
        for (int r = 1; r < 32; ++r) acc += bins[r * STRIDE + tid];
        const int t = (tid < NC) ? tid : tid - NC;        // class
        const int c = (tid < NC) ? c0 : c0 + 1;           // channel col; g=9,hi -> 19 = counts
        S_part[(((size_t)(b * CHUNKS + chunk)) * NC + t) * 20 + c] = acc;
    }
}

__global__ __launch_bounds__(FT) void finalize_kernel(const float* __restrict__ S_part,
                                                      float* __restrict__ out) {
    __shared__ float S[NB * NC * 20];  // 3040 floats: S[b][t][c], col 19 = count
    __shared__ float wsum[FT / 64];
    const int tid = threadIdx.x;

    // Phase A: reduce the 16 chunk partials (coalesced: r is contiguous).
    for (int e = tid; e < NB * NC * 20; e += FT) {
        const int b = e / (NC * 20);
        const int r = e - b * NC * 20;
        float a = 0.0f;
        #pragma unroll
        for (int ch = 0; ch < CHUNKS; ++ch)
            a += S_part[((size_t)(b * CHUNKS + ch)) * (NC * 20) + r];
        S[e] = a;
    }
    __syncthreads();

    // Phase B: 2888 log terms.
    const float eps = 2.220446049250313e-16f;  // np.spacing(1)
    float local = 0.0f;
    for (int idx = tid; idx < NB * NC * NC; idx += FT) {
        const int b = idx / (NC * NC);
        const int r = idx - b * NC * NC;
        const int i = r / NC;
        const int k = r - i * NC;
        const float* Sb = S + b * NC * 20;
        const float cnt_i = Sb[i * 20 + 19];
        const float cnt_k = Sb[k * 20 + 19];
        const float alpha = (cnt_i > 0.0f) ? Sb[i * 20 + i] / cnt_i : 0.0f;
        const float beta = (cnt_k > 0.0f) ? 1.0f - Sb[k * 20 + i] / cnt_k : 0.0f;
        local += logf(0.5f * (alpha + beta + eps));
    }

    #pragma unroll
    for (int off = 32; off > 0; off >>= 1) local += __shfl_down(local, off);
    if ((tid & 63) == 0) wsum[tid >> 6] = local;
    __syncthreads();
    if (tid == 0) {
        float t = 0.0f;
        #pragma unroll
        for (int w = 0; w < FT / 64; ++w) t += wsum[w];
        out[0] = -0.5f * t / (float)NB;
    }
}

extern "C" void kernel_launch(void* const* d_in, const int* in_sizes, int n_in,
                              void* d_out, int out_size, void* d_ws, size_t ws_size,
                              hipStream_t stream) {
    const float* seg = (const float*)d_in[0];
    const int* tgt = (const int*)d_in[1];
    float* S_part = (float*)d_ws;  // 194,560 B; every slot written unconditionally

    dim3 grid(NBLK);  // 1D; XCD-tile swizzle done in-kernel
    accum_kernel<<<grid, TPB, 0, stream>>>(seg, tgt, S_part);
    finalize_kernel<<<1, FT, 0, stream>>>(S_part, (float*)d_out);
}